// Round 1
// baseline (467.715 us; speedup 1.0000x reference)
//
#include <hip/hip_runtime.h>

// Direct 3x3 conv, NCHW fp32. N=32, C_IN=3, H=W=224, C_OUT=64, stride 1, pad 1.
// v2: one thread per 1x4 output-pixel strip x 16 c_out (c_out chunk = blockIdx.z).
//  - float4 window loads + float4 stores (4x fewer store instrs than v1)
//  - 54-float input window amortized over 4 pixels
//  - 4 independent accumulator chains per weight (hides v_fmac latency)
//  - weights/bias are wave-uniform -> scalar (s_load) path
// Accumulation order per output matches v1 (bias, then ci-major, dh, dw) so
// numerics/absmax are identical.

#define N_IMG 32
#define C_IN 3
#define H_ 224
#define W_ 224
#define C_OUT 64
#define NPIX (H_ * W_)          // 50176
#define W4 (W_ / 4)             // 56 strips per row
#define STRIPS (NPIX / 4)       // 12544 = 49 * 256
#define COB 16                  // c_out per block chunk (gridDim.z = 4)

__global__ __launch_bounds__(256) void conv3x3_v2(
    const float* __restrict__ x,      // [N, C_IN, H, W]
    const float* __restrict__ wgt,    // [C_OUT, C_IN, 3, 3]
    const float* __restrict__ bias,   // [C_OUT]
    float* __restrict__ out)          // [N, C_OUT, H, W]
{
    const int s  = blockIdx.x * 256 + threadIdx.x;  // strip index within image
    const int n  = blockIdx.y;
    const int cb = blockIdx.z * COB;                // first c_out of this chunk
    const int h  = s / W4;
    const int w4 = (s - h * W4) * 4;                // leftmost pixel column

    // 3 cin x 3 rows x 6 cols input window; col 0 corresponds to w4-1.
    float win[C_IN][3][6];
    const float* xn = x + (size_t)n * C_IN * NPIX;
#pragma unroll
    for (int ci = 0; ci < C_IN; ++ci) {
#pragma unroll
        for (int r = 0; r < 3; ++r) {
            const int hh = h + r - 1;
            const bool hok = (unsigned)hh < (unsigned)H_;
            const float* row = xn + ci * NPIX + hh * W_;
            if (hok) {
                // middle 4 cols: always in-bounds, 16B-aligned
                const float4 m = *reinterpret_cast<const float4*>(row + w4);
                win[ci][r][1] = m.x; win[ci][r][2] = m.y;
                win[ci][r][3] = m.z; win[ci][r][4] = m.w;
                win[ci][r][0] = (w4 > 0)      ? row[w4 - 1] : 0.0f;
                win[ci][r][5] = (w4 + 4 < W_) ? row[w4 + 4] : 0.0f;
            } else {
#pragma unroll
                for (int c = 0; c < 6; ++c) win[ci][r][c] = 0.0f;
            }
        }
    }

    float* outp = out + ((size_t)n * C_OUT + cb) * NPIX + h * W_ + w4;
#pragma unroll
    for (int i = 0; i < COB; ++i) {
        const float* wp = wgt + (size_t)(cb + i) * 27;
        const float b  = bias[cb + i];
        float a0 = b, a1 = b, a2 = b, a3 = b;
#pragma unroll
        for (int ci = 0; ci < C_IN; ++ci)
#pragma unroll
            for (int r = 0; r < 3; ++r)
#pragma unroll
                for (int dc = 0; dc < 3; ++dc) {
                    const float wv = wp[(ci * 3 + r) * 3 + dc];
                    a0 += win[ci][r][0 + dc] * wv;
                    a1 += win[ci][r][1 + dc] * wv;
                    a2 += win[ci][r][2 + dc] * wv;
                    a3 += win[ci][r][3 + dc] * wv;
                }
        float4 o; o.x = a0; o.y = a1; o.z = a2; o.w = a3;
        *reinterpret_cast<float4*>(outp + (size_t)i * NPIX) = o;
    }
}

extern "C" void kernel_launch(void* const* d_in, const int* in_sizes, int n_in,
                              void* d_out, int out_size, void* d_ws, size_t ws_size,
                              hipStream_t stream) {
    const float* x    = (const float*)d_in[0];
    const float* wgt  = (const float*)d_in[1];
    const float* bias = (const float*)d_in[2];
    float* out = (float*)d_out;

    dim3 grid(STRIPS / 256, N_IMG, C_OUT / COB);   // 49 x 32 x 4 blocks
    dim3 block(256);
    conv3x3_v2<<<grid, block, 0, stream>>>(x, wgt, bias, out);
}